// Round 2
// baseline (1096.263 us; speedup 1.0000x reference)
//
#include <hip/hip_runtime.h>
#include <hip/hip_bf16.h>
#include <stdint.h>

#define N_NODES 50000
#define N_EDGES 800000
#define IN_CH 256
#define HID 128
#define OUT_CH 64
#define EDGE_DIM 64

// agg_fused geometry: one block per 64-edge window of the dst-sorted edge list.
#define AGG_EW  64                   // base edge window per block
#define AGG_CAP 128                  // max edges touched (window + tail segment; maxdeg~45)
#define AGG_B   (N_EDGES / AGG_EW)   // 12500 (divides exactly)

typedef __hip_bfloat16 bf16;
typedef __attribute__((ext_vector_type(8))) short short8;
typedef __attribute__((ext_vector_type(4))) float f32x4;

__device__ __forceinline__ void st_out(float* p, float v) { *p = v; }
__device__ __forceinline__ void st_out(bf16* p, float v) { *p = __float2bfloat16(v); }

// ---- one-shot weight prep: transpose + bf16 for all 5 weight matrices ----
// Wt[n*K + k] = bf16(W[k*N + n])
__device__ __forceinline__ void wt_one(const float* W, bf16* Wt, int K, int N, int i) {
    int n = i % N, k = i / N;
    Wt[n * K + k] = __float2bfloat16(W[i]);
}
__launch_bounds__(256)
__global__ void wt_prep_all(const float* W_in, const float* W_e, const float* W1,
                            const float* W2, const float* W_out,
                            bf16* Wt_in, bf16* Wt_e, bf16* Wt_1, bf16* Wt_2, bf16* Wt_out) {
    int i = blockIdx.x * 256 + threadIdx.x;
    if (i < 32768)       wt_one(W_in,  Wt_in,  256, 128, i);
    else if (i < 40960)  wt_one(W_e,   Wt_e,    64, 128, i - 32768);
    else if (i < 57344)  wt_one(W1,    Wt_1,   128, 128, i - 40960);
    else if (i < 73728)  wt_one(W2,    Wt_2,   128, 128, i - 57344);
    else if (i < 81920)  wt_one(W_out, Wt_out, 128,  64, i - 73728);
}

// MFMA GEMM: out[r, c] = act( A[r,:] @ W[:,c] + b[c] )
// A: InT [M x KTOT] row-major (fp32 converted at staging, bf16 copied).
// Wt: bf16 [N x KTOT] pre-transposed. 256 thr = 4 waves; MROWS-row block tile.
template<int KTOT, int N, int MROWS, bool RELU, typename InT, typename OutT>
__launch_bounds__(256)
__global__ void gemm_mfma(const InT* __restrict__ A, const bf16* __restrict__ Wt,
                          const float* __restrict__ b, OutT* __restrict__ out, int M) {
    static_assert(KTOT % 64 == 0, "");
    constexpr int KC  = 64;
    constexpr int NCH = KTOT / KC;
    constexpr int KCP = KC + 8;            // 72: row = 144 B (16B-aligned, 2-way bank alias = free)
    constexpr int NT  = N / 16;
    constexpr int MT  = MROWS / 64;        // m-tiles per wave
    __shared__ __align__(16) bf16 Ws[N * KCP];
    __shared__ __align__(16) bf16 As[MROWS * KCP];

    const int tid  = threadIdx.x;
    const int wave = tid >> 6;
    const int lane = tid & 63;
    const int quad = lane >> 4;
    const int l16  = lane & 15;
    const int base = blockIdx.x * MROWS;

    f32x4 acc[MT][NT];
    #pragma unroll
    for (int m = 0; m < MT; m++)
        #pragma unroll
        for (int i = 0; i < NT; i++) acc[m][i] = (f32x4){0.f, 0.f, 0.f, 0.f};

    for (int ch = 0; ch < NCH; ch++) {
        const int kc = ch * KC;
        // stage weight chunk (bf16 16B copies)
        constexpr int WIT = N * KC / (256 * 8);
        #pragma unroll
        for (int it = 0; it < WIT; it++) {
            int t8 = (it * 256 + tid) * 8;
            int n = t8 / KC, k = t8 % KC;
            *(uint4*)&Ws[n * KCP + k] = *(const uint4*)&Wt[n * KTOT + kc + k];
        }
        // stage A chunk
        if constexpr (sizeof(InT) == 4) {
            constexpr int AIT = MROWS * KC / (256 * 4);
            #pragma unroll
            for (int it = 0; it < AIT; it++) {
                int t4 = (it * 256 + tid) * 4;
                int r = t4 / KC, k = t4 % KC;
                int gr = base + r;
                float4 v = (gr < M) ? *(const float4*)&A[(size_t)gr * KTOT + kc + k]
                                    : make_float4(0.f, 0.f, 0.f, 0.f);
                *(__hip_bfloat162*)&As[r * KCP + k]     = __float22bfloat162_rn(make_float2(v.x, v.y));
                *(__hip_bfloat162*)&As[r * KCP + k + 2] = __float22bfloat162_rn(make_float2(v.z, v.w));
            }
        } else {
            constexpr int AIT = MROWS * KC / (256 * 8);
            #pragma unroll
            for (int it = 0; it < AIT; it++) {
                int t8 = (it * 256 + tid) * 8;
                int r = t8 / KC, k = t8 % KC;
                int gr = base + r;
                uint4 v = (gr < M) ? *(const uint4*)&A[(size_t)gr * KTOT + kc + k]
                                   : make_uint4(0u, 0u, 0u, 0u);
                *(uint4*)&As[r * KCP + k] = v;
            }
        }
        __syncthreads();

        #pragma unroll
        for (int ks = 0; ks < KC / 32; ks++) {
            short8 af[MT];
            #pragma unroll
            for (int m = 0; m < MT; m++)
                af[m] = *(const short8*)&As[(wave * MT * 16 + m * 16 + l16) * KCP + ks * 32 + quad * 8];
            #pragma unroll
            for (int nt = 0; nt < NT; nt++) {
                short8 bfr = *(const short8*)&Ws[(nt * 16 + l16) * KCP + ks * 32 + quad * 8];
                #pragma unroll
                for (int m = 0; m < MT; m++)
                    acc[m][nt] = __builtin_amdgcn_mfma_f32_16x16x32_bf16(af[m], bfr, acc[m][nt], 0, 0, 0);
            }
        }
        __syncthreads();
    }

    // epilogue: C/D layout col=lane&15, row=quad*4+reg ; coalesced sequential rows
    #pragma unroll
    for (int m = 0; m < MT; m++) {
        const int r0 = base + wave * MT * 16 + m * 16 + quad * 4;
        #pragma unroll
        for (int reg = 0; reg < 4; reg++) {
            int gr = r0 + reg;
            if (gr < M) {
                #pragma unroll
                for (int nt = 0; nt < NT; nt++) {
                    int col = nt * 16 + l16;
                    float v = acc[m][nt][reg] + b[col];
                    if (RELU) v = fmaxf(v, 0.f);
                    st_out(&out[(size_t)gr * N + col], v);
                }
            }
        }
    }
}

// ---- counting sort of edges by dst ----
__launch_bounds__(256)
__global__ void hist_kernel(const int* __restrict__ ei, int* __restrict__ counts) {
    int edge = blockIdx.x * 256 + threadIdx.x;
    if (edge < N_EDGES) atomicAdd(&counts[ei[N_EDGES + edge]], 1);
}

// scan + blkstart: blkstart[b] = first node n with offsets[n] >= b*AGG_EW
__launch_bounds__(1024)
__global__ void scan_kernel(const int* __restrict__ counts, int* __restrict__ offsets,
                            int* __restrict__ cursor, int* __restrict__ blkstart) {
    __shared__ int part[1024];
    const int tid = threadIdx.x;
    const int CH = (N_NODES + 1023) / 1024;
    int beg = tid * CH, end = min(beg + CH, N_NODES);
    int s = 0;
    for (int i = beg; i < end; i++) s += counts[i];
    part[tid] = s;
    __syncthreads();
    for (int off = 1; off < 1024; off <<= 1) {
        int t = (tid >= off) ? part[tid - off] : 0;
        __syncthreads();
        part[tid] += t;
        __syncthreads();
    }
    int run = (tid == 0) ? 0 : part[tid - 1];
    for (int i = beg; i < end; i++) {
        offsets[i] = run;
        cursor[i] = run;
        run += counts[i];
    }
    if (tid == 1023) offsets[N_NODES] = part[1023];
    __syncthreads();   // offsets globally visible within block
    // blkstart: node n owns blocks b with offsets[n-1] < b*EW <= offsets[n]
    int vp = (beg == 0) ? -1 : offsets[beg - 1];
    for (int n = beg; n < end; n++) {
        int v = offsets[n];
        int blo_ = (vp < 0) ? 0 : (vp / AGG_EW + 1);
        int bhi_ = v / AGG_EW;
        for (int bb = blo_; bb <= bhi_; bb++) blkstart[bb] = n;
        vp = v;
    }
    if (tid == 1023) {
        int vpN = offsets[N_NODES - 1];
        int blo_ = vpN / AGG_EW + 1;
        for (int bb = blo_; bb <= AGG_B; bb++) blkstart[bb] = N_NODES;
        blkstart[AGG_B + 1] = N_NODES;
    }
}

// poe[edge] = sorted position; srcs[pos] = src node of edge at sorted pos
__launch_bounds__(256)
__global__ void scatter_perm(const int* __restrict__ ei, int* __restrict__ cursor,
                             int* __restrict__ poe, int* __restrict__ srcs) {
    int edge = blockIdx.x * 256 + threadIdx.x;
    if (edge >= N_EDGES) return;
    int dst = ei[N_EDGES + edge];
    int pos = atomicAdd(&cursor[dst], 1);
    poe[edge] = pos;
    srcs[pos] = ei[edge];
}

// eas[poe[edge]] = bf16(ea[edge])  — coalesced read, scattered 128-B row write
__launch_bounds__(256)
__global__ void ea_permute(const float* __restrict__ ea, const int* __restrict__ poe,
                           bf16* __restrict__ eas) {
    int t = blockIdx.x * 256 + threadIdx.x;
    int edge = t >> 4, l16 = t & 15;
    if (edge >= N_EDGES) return;
    float4 v = *(const float4*)&ea[(size_t)edge * EDGE_DIM + l16 * 4];
    int pos = poe[edge];
    __hip_bfloat162 p0 = __float22bfloat162_rn(make_float2(v.x, v.y));
    __hip_bfloat162 p1 = __float22bfloat162_rn(make_float2(v.z, v.w));
    uint2 u = make_uint2(*(uint32_t*)&p0, *(uint32_t*)&p1);
    *(uint2*)&eas[(size_t)pos * EDGE_DIM + l16 * 4] = u;
}

// ---- fused edge-projection + segmented aggregation ----
// z[n] = h[n] + sum_{pos in seg(n)} relu(h[srcs[pos]] + eas[pos] @ W_e + b_e)
// Block b owns nodes with floor(offsets[n]/EW)==b (range via blkstart), edges
// [offsets[n0], offsets[n1]) <= CAP. Phase 1: MFMA e-rows -> LDS. Phase 2: seg-sum.
__device__ __forceinline__ float blo(uint32_t u) { return __uint_as_float(u << 16); }
__device__ __forceinline__ float bhi(uint32_t u) { return __uint_as_float(u & 0xffff0000u); }

__launch_bounds__(256)
__global__ void agg_fused(const int* __restrict__ offsets, const int* __restrict__ blkstart,
                          const int* __restrict__ srcs, const bf16* __restrict__ eas,
                          const bf16* __restrict__ Wt_e, const float* __restrict__ b_e,
                          const bf16* __restrict__ h, bf16* __restrict__ z) {
    constexpr int P = 136;                         // et pitch (bf16 elems), row = 272 B
    __shared__ __align__(16) bf16 et[AGG_CAP * P]; // 34.8 KB
    __shared__ int srcs_s[AGG_CAP];

    const int b    = blockIdx.x;
    const int tid  = threadIdx.x;
    const int wave = tid >> 6;
    const int lane = tid & 63;
    const int quad = lane >> 4;
    const int l16  = lane & 15;

    const int n0 = blkstart[b], n1 = blkstart[b + 1];
    if (n0 >= n1) return;                          // uniform: safe before barriers
    const int e0 = offsets[n0];
    int e1 = offsets[n1];
    if (e1 > e0 + AGG_CAP) e1 = e0 + AGG_CAP;      // unreachable for maxdeg<64
    const int ne = e1 - e0;

    if (tid < AGG_CAP) srcs_s[tid] = (tid < ne) ? srcs[e0 + tid] : 0;

    // ---- phase 1: e-tile = eas[e0..e1) @ W_e + b_e  (D[ch, edge] layout) ----
    // wave handles 2 channel-16-tiles: ch groups (wave*2+ct)*16
    short8 af[2][2];     // [ct][ks] : Wt_e rows (A operand)
    float4 bias[2];
    #pragma unroll
    for (int ct = 0; ct < 2; ct++) {
        int chr = (wave * 2 + ct) * 16 + l16;      // A row = out channel
        #pragma unroll
        for (int ks = 0; ks < 2; ks++)
            af[ct][ks] = *(const short8*)&Wt_e[chr * EDGE_DIM + ks * 32 + quad * 8];
        bias[ct] = *(const float4*)&b_e[(wave * 2 + ct) * 16 + quad * 4];
    }
    const int nsub = (ne + 15) >> 4;
    for (int es = 0; es < nsub; es++) {
        int erow = es * 16 + l16;                  // B row = edge (local)
        int ge = e0 + erow;
        short8 bf0 = (short8){0,0,0,0,0,0,0,0}, bf1 = bf0;
        if (erow < ne) {
            bf0 = *(const short8*)&eas[(size_t)ge * EDGE_DIM + quad * 8];
            bf1 = *(const short8*)&eas[(size_t)ge * EDGE_DIM + 32 + quad * 8];
        }
        #pragma unroll
        for (int ct = 0; ct < 2; ct++) {
            f32x4 acc = (f32x4){0.f, 0.f, 0.f, 0.f};
            acc = __builtin_amdgcn_mfma_f32_16x16x32_bf16(af[ct][0], bf0, acc, 0, 0, 0);
            acc = __builtin_amdgcn_mfma_f32_16x16x32_bf16(af[ct][1], bf1, acc, 0, 0, 0);
            // lane holds edge = es*16+l16 (col), ch = (wave*2+ct)*16 + quad*4 + reg (row)
            int row = es * 16 + l16;
            int ch0 = (wave * 2 + ct) * 16 + quad * 4;
            __hip_bfloat162 p0 = __float22bfloat162_rn(make_float2(acc[0] + bias[ct].x, acc[1] + bias[ct].y));
            __hip_bfloat162 p1 = __float22bfloat162_rn(make_float2(acc[2] + bias[ct].z, acc[3] + bias[ct].w));
            *(uint2*)&et[row * P + ch0] = make_uint2(*(uint32_t*)&p0, *(uint32_t*)&p1);
        }
    }
    __syncthreads();

    // ---- phase 2: segmented sum per node, e from LDS ----
    const int c = lane * 2;
    for (int n = n0 + wave; n < n1; n += 4) {
        int s  = offsets[n] - e0;
        int ee = offsets[n + 1] - e0;
        if (ee > ne) ee = ne;                      // paranoia (clamped case)
        float2 a = make_float2(0.f, 0.f);
        int i = s;
        for (; i + 1 < ee; i += 2) {
            int s0 = srcs_s[i], s1 = srcs_s[i + 1];
            uint32_t ev0 = *(const uint32_t*)&et[i * P + c];
            uint32_t ev1 = *(const uint32_t*)&et[(i + 1) * P + c];
            uint32_t h0 = *(const uint32_t*)&h[(size_t)s0 * HID + c];
            uint32_t h1 = *(const uint32_t*)&h[(size_t)s1 * HID + c];
            a.x += fmaxf(blo(h0) + blo(ev0), 0.f);
            a.y += fmaxf(bhi(h0) + bhi(ev0), 0.f);
            a.x += fmaxf(blo(h1) + blo(ev1), 0.f);
            a.y += fmaxf(bhi(h1) + bhi(ev1), 0.f);
        }
        if (i < ee) {
            int s0 = srcs_s[i];
            uint32_t ev0 = *(const uint32_t*)&et[i * P + c];
            uint32_t h0 = *(const uint32_t*)&h[(size_t)s0 * HID + c];
            a.x += fmaxf(blo(h0) + blo(ev0), 0.f);
            a.y += fmaxf(bhi(h0) + bhi(ev0), 0.f);
        }
        uint32_t hn = *(const uint32_t*)&h[(size_t)n * HID + c];
        a.x += blo(hn);
        a.y += bhi(hn);
        __hip_bfloat162 p = __float22bfloat162_rn(make_float2(a.x, a.y));
        *(uint32_t*)&z[(size_t)n * HID + c] = *(uint32_t*)&p;
    }
}

extern "C" void kernel_launch(void* const* d_in, const int* in_sizes, int n_in,
                              void* d_out, int out_size, void* d_ws, size_t ws_size,
                              hipStream_t stream) {
    const float* x     = (const float*)d_in[0];
    const int*   ei    = (const int*)d_in[1];
    const float* ea    = (const float*)d_in[2];
    const float* W_in  = (const float*)d_in[3];
    const float* b_in  = (const float*)d_in[4];
    const float* W_e   = (const float*)d_in[5];
    const float* b_e   = (const float*)d_in[6];
    const float* W1    = (const float*)d_in[7];
    const float* b1    = (const float*)d_in[8];
    const float* W2    = (const float*)d_in[9];
    const float* b2    = (const float*)d_in[10];
    const float* W_out = (const float*)d_in[11];
    const float* b_out = (const float*)d_in[12];
    float* out = (float*)d_out;

    char* ws = (char*)d_ws;
    size_t off = 0;
    bf16*  h        = (bf16*) (ws + off); off += (size_t)N_NODES * HID * 2;      // 12.8 MB
    bf16*  z        = (bf16*) (ws + off); off += (size_t)N_NODES * HID * 2;      // 12.8 MB
    bf16*  eas      = (bf16*) (ws + off); off += (size_t)N_EDGES * EDGE_DIM * 2; // 102.4 MB
    int*   counts   = (int*)  (ws + off); off += (size_t)N_NODES * 4;
    int*   offsets  = (int*)  (ws + off); off += (size_t)(N_NODES + 1) * 4;
    int*   cursor   = (int*)  (ws + off); off += (size_t)N_NODES * 4;
    int*   poe      = (int*)  (ws + off); off += (size_t)N_EDGES * 4;
    int*   srcs     = (int*)  (ws + off); off += (size_t)N_EDGES * 4;
    int*   blkstart = (int*)  (ws + off); off += (size_t)(AGG_B + 2) * 4;
    bf16*  Wt_in    = (bf16*) (ws + off); off += (size_t)HID * IN_CH * 2;
    bf16*  Wt_e     = (bf16*) (ws + off); off += (size_t)HID * EDGE_DIM * 2;
    bf16*  Wt_1     = (bf16*) (ws + off); off += (size_t)HID * HID * 2;
    bf16*  Wt_2     = (bf16*) (ws + off); off += (size_t)HID * HID * 2;
    bf16*  Wt_out   = (bf16*) (ws + off); off += (size_t)OUT_CH * HID * 2;

    // ---- weight prep (one kernel) ----
    wt_prep_all<<<(81920 + 255) / 256, 256, 0, stream>>>(
        W_in, W_e, W1, W2, W_out, Wt_in, Wt_e, Wt_1, Wt_2, Wt_out);

    // ---- counting sort by dst + block ownership table ----
    hipMemsetAsync(counts, 0, (size_t)N_NODES * 4, stream);
    hist_kernel<<<(N_EDGES + 255) / 256, 256, 0, stream>>>(ei, counts);
    scan_kernel<<<1, 1024, 0, stream>>>(counts, offsets, cursor, blkstart);
    scatter_perm<<<(N_EDGES + 255) / 256, 256, 0, stream>>>(ei, cursor, poe, srcs);

    // ---- eas = bf16(ea) permuted into sorted order ----
    ea_permute<<<(N_EDGES * 16 + 255) / 256, 256, 0, stream>>>(ea, poe, eas);

    // h = x @ W_in + b_in   (fp32 in, bf16 out)
    gemm_mfma<IN_CH, HID, 64, false, float, bf16>
        <<<(N_NODES + 63) / 64, 256, 0, stream>>>(x, Wt_in, b_in, h, N_NODES);

    for (int layer = 0; layer < 3; ++layer) {
        agg_fused<<<AGG_B + 1, 256, 0, stream>>>(offsets, blkstart, srcs, eas, Wt_e, b_e, h, z);
        gemm_mfma<HID, HID, 64, true, bf16, bf16>
            <<<(N_NODES + 63) / 64, 256, 0, stream>>>(z, Wt_1, b1, h, N_NODES);
        gemm_mfma<HID, HID, 64, true, bf16, bf16>
            <<<(N_NODES + 63) / 64, 256, 0, stream>>>(h, Wt_2, b2, z, N_NODES);
        bf16* t = h; h = z; z = t;   // next layer's h is g2's output
    }

    // out = h @ W_out + b_out (fp32 out)
    gemm_mfma<HID, OUT_CH, 64, false, bf16, float>
        <<<(N_NODES + 63) / 64, 256, 0, stream>>>(h, Wt_out, b_out, out, N_NODES);
}

// Round 3
// 884.730 us; speedup vs baseline: 1.2391x; 1.2391x over previous
//
#include <hip/hip_runtime.h>
#include <hip/hip_bf16.h>
#include <stdint.h>

#define N_NODES 50000
#define N_EDGES 800000
#define IN_CH 256
#define HID 128
#define OUT_CH 64
#define EDGE_DIM 64

// agg_fused geometry: one block per 64-edge window of the dst-sorted edge list.
#define AGG_EW  64                   // base edge window per block
#define AGG_CAP 128                  // max edges touched (window + tail segment; maxdeg~45)
#define AGG_B   (N_EDGES / AGG_EW)   // 12500 (divides exactly)
#define SCB     196                  // scan blocks: ceil(N_NODES/256)

typedef __hip_bfloat16 bf16;
typedef __attribute__((ext_vector_type(8))) short short8;
typedef __attribute__((ext_vector_type(4))) float f32x4;

__device__ __forceinline__ void st_out(float* p, float v) { *p = v; }
__device__ __forceinline__ void st_out(bf16* p, float v) { *p = __float2bfloat16(v); }

// ---- one-shot weight prep: transpose + bf16 for all 5 weight matrices ----
// Wt[n*K + k] = bf16(W[k*N + n])
__device__ __forceinline__ void wt_one(const float* W, bf16* Wt, int K, int N, int i) {
    int n = i % N, k = i / N;
    Wt[n * K + k] = __float2bfloat16(W[i]);
}
__launch_bounds__(256)
__global__ void wt_prep_all(const float* W_in, const float* W_e, const float* W1,
                            const float* W2, const float* W_out,
                            bf16* Wt_in, bf16* Wt_e, bf16* Wt_1, bf16* Wt_2, bf16* Wt_out) {
    int i = blockIdx.x * 256 + threadIdx.x;
    if (i < 32768)       wt_one(W_in,  Wt_in,  256, 128, i);
    else if (i < 40960)  wt_one(W_e,   Wt_e,    64, 128, i - 32768);
    else if (i < 57344)  wt_one(W1,    Wt_1,   128, 128, i - 40960);
    else if (i < 73728)  wt_one(W2,    Wt_2,   128, 128, i - 57344);
    else if (i < 81920)  wt_one(W_out, Wt_out, 128,  64, i - 73728);
}

// MFMA GEMM: out[r, c] = act( A[r,:] @ W[:,c] + b[c] )
template<int KTOT, int N, int MROWS, bool RELU, typename InT, typename OutT>
__launch_bounds__(256)
__global__ void gemm_mfma(const InT* __restrict__ A, const bf16* __restrict__ Wt,
                          const float* __restrict__ b, OutT* __restrict__ out, int M) {
    static_assert(KTOT % 64 == 0, "");
    constexpr int KC  = 64;
    constexpr int NCH = KTOT / KC;
    constexpr int KCP = KC + 8;            // 72: row = 144 B (16B-aligned, 2-way bank alias = free)
    constexpr int NT  = N / 16;
    constexpr int MT  = MROWS / 64;        // m-tiles per wave
    __shared__ __align__(16) bf16 Ws[N * KCP];
    __shared__ __align__(16) bf16 As[MROWS * KCP];

    const int tid  = threadIdx.x;
    const int wave = tid >> 6;
    const int lane = tid & 63;
    const int quad = lane >> 4;
    const int l16  = lane & 15;
    const int base = blockIdx.x * MROWS;

    f32x4 acc[MT][NT];
    #pragma unroll
    for (int m = 0; m < MT; m++)
        #pragma unroll
        for (int i = 0; i < NT; i++) acc[m][i] = (f32x4){0.f, 0.f, 0.f, 0.f};

    for (int ch = 0; ch < NCH; ch++) {
        const int kc = ch * KC;
        constexpr int WIT = N * KC / (256 * 8);
        #pragma unroll
        for (int it = 0; it < WIT; it++) {
            int t8 = (it * 256 + tid) * 8;
            int n = t8 / KC, k = t8 % KC;
            *(uint4*)&Ws[n * KCP + k] = *(const uint4*)&Wt[n * KTOT + kc + k];
        }
        if constexpr (sizeof(InT) == 4) {
            constexpr int AIT = MROWS * KC / (256 * 4);
            #pragma unroll
            for (int it = 0; it < AIT; it++) {
                int t4 = (it * 256 + tid) * 4;
                int r = t4 / KC, k = t4 % KC;
                int gr = base + r;
                float4 v = (gr < M) ? *(const float4*)&A[(size_t)gr * KTOT + kc + k]
                                    : make_float4(0.f, 0.f, 0.f, 0.f);
                *(__hip_bfloat162*)&As[r * KCP + k]     = __float22bfloat162_rn(make_float2(v.x, v.y));
                *(__hip_bfloat162*)&As[r * KCP + k + 2] = __float22bfloat162_rn(make_float2(v.z, v.w));
            }
        } else {
            constexpr int AIT = MROWS * KC / (256 * 8);
            #pragma unroll
            for (int it = 0; it < AIT; it++) {
                int t8 = (it * 256 + tid) * 8;
                int r = t8 / KC, k = t8 % KC;
                int gr = base + r;
                uint4 v = (gr < M) ? *(const uint4*)&A[(size_t)gr * KTOT + kc + k]
                                   : make_uint4(0u, 0u, 0u, 0u);
                *(uint4*)&As[r * KCP + k] = v;
            }
        }
        __syncthreads();

        #pragma unroll
        for (int ks = 0; ks < KC / 32; ks++) {
            short8 af[MT];
            #pragma unroll
            for (int m = 0; m < MT; m++)
                af[m] = *(const short8*)&As[(wave * MT * 16 + m * 16 + l16) * KCP + ks * 32 + quad * 8];
            #pragma unroll
            for (int nt = 0; nt < NT; nt++) {
                short8 bfr = *(const short8*)&Ws[(nt * 16 + l16) * KCP + ks * 32 + quad * 8];
                #pragma unroll
                for (int m = 0; m < MT; m++)
                    acc[m][nt] = __builtin_amdgcn_mfma_f32_16x16x32_bf16(af[m], bfr, acc[m][nt], 0, 0, 0);
            }
        }
        __syncthreads();
    }

    #pragma unroll
    for (int m = 0; m < MT; m++) {
        const int r0 = base + wave * MT * 16 + m * 16 + quad * 4;
        #pragma unroll
        for (int reg = 0; reg < 4; reg++) {
            int gr = r0 + reg;
            if (gr < M) {
                #pragma unroll
                for (int nt = 0; nt < NT; nt++) {
                    int col = nt * 16 + l16;
                    float v = acc[m][nt][reg] + b[col];
                    if (RELU) v = fmaxf(v, 0.f);
                    st_out(&out[(size_t)gr * N + col], v);
                }
            }
        }
    }
}

// ---- counting sort of edges by dst ----
__launch_bounds__(256)
__global__ void hist_kernel(const int* __restrict__ ei, int* __restrict__ counts) {
    int edge = blockIdx.x * 256 + threadIdx.x;
    if (edge < N_EDGES) atomicAdd(&counts[ei[N_EDGES + edge]], 1);
}

// ---- parallel two-level scan (replaces the 172 us serial scan_kernel) ----
__launch_bounds__(256)
__global__ void scan_a(const int* __restrict__ counts, int* __restrict__ bsum) {
    __shared__ int sh[256];
    const int tid = threadIdx.x;
    int n = blockIdx.x * 256 + tid;
    sh[tid] = (n < N_NODES) ? counts[n] : 0;
    __syncthreads();
    for (int off = 128; off > 0; off >>= 1) {
        if (tid < off) sh[tid] += sh[tid + off];
        __syncthreads();
    }
    if (tid == 0) bsum[blockIdx.x] = sh[0];
}

__launch_bounds__(256)
__global__ void scan_b(const int* __restrict__ bsum, int* __restrict__ bpre) {
    __shared__ int sh[256];
    const int tid = threadIdx.x;
    int v = (tid < SCB) ? bsum[tid] : 0;
    sh[tid] = v;
    __syncthreads();
    for (int off = 1; off < 256; off <<= 1) {
        int t = (tid >= off) ? sh[tid - off] : 0;
        __syncthreads();
        sh[tid] += t;
        __syncthreads();
    }
    if (tid < SCB) bpre[tid] = sh[tid] - v;   // exclusive
}

__launch_bounds__(256)
__global__ void scan_c(const int* __restrict__ counts, const int* __restrict__ bpre,
                       int* __restrict__ offsets, int* __restrict__ cursor) {
    __shared__ int sh[256];
    const int tid = threadIdx.x;
    int n = blockIdx.x * 256 + tid;
    int c = (n < N_NODES) ? counts[n] : 0;
    sh[tid] = c;
    __syncthreads();
    for (int off = 1; off < 256; off <<= 1) {
        int t = (tid >= off) ? sh[tid - off] : 0;
        __syncthreads();
        sh[tid] += t;
        __syncthreads();
    }
    if (n < N_NODES) {
        int excl = bpre[blockIdx.x] + sh[tid] - c;
        offsets[n] = excl;
        cursor[n]  = excl;
    }
    if (blockIdx.x == 0 && tid == 0) offsets[N_NODES] = N_EDGES;  // total by construction
}

// blkstart[b] = first node n with offsets[n] >= b*AGG_EW.
// Node n writes range (offsets[n-1]/EW, offsets[n]/EW] — disjoint across n, race-free.
__launch_bounds__(256)
__global__ void scan_d(const int* __restrict__ offsets, int* __restrict__ blkstart) {
    int n = blockIdx.x * 256 + threadIdx.x;
    if (n > N_NODES) return;
    int v = (n == N_NODES) ? N_EDGES : offsets[n];
    int lo = 0;
    if (n > 0) lo = offsets[n - 1] / AGG_EW + 1;
    int hi = v / AGG_EW;
    for (int bb = lo; bb <= hi; bb++) blkstart[bb] = n;
    if (n == N_NODES) blkstart[AGG_B + 1] = N_NODES;
}

// poe[edge] = sorted position; srcs[pos] = src node of edge at sorted pos
__launch_bounds__(256)
__global__ void scatter_perm(const int* __restrict__ ei, int* __restrict__ cursor,
                             int* __restrict__ poe, int* __restrict__ srcs) {
    int edge = blockIdx.x * 256 + threadIdx.x;
    if (edge >= N_EDGES) return;
    int dst = ei[N_EDGES + edge];
    int pos = atomicAdd(&cursor[dst], 1);
    poe[edge] = pos;
    srcs[pos] = ei[edge];
}

// eas[poe[edge]] = bf16(ea[edge])  — coalesced read, scattered 128-B row write
__launch_bounds__(256)
__global__ void ea_permute(const float* __restrict__ ea, const int* __restrict__ poe,
                           bf16* __restrict__ eas) {
    int t = blockIdx.x * 256 + threadIdx.x;
    int edge = t >> 4, l16 = t & 15;
    if (edge >= N_EDGES) return;
    float4 v = *(const float4*)&ea[(size_t)edge * EDGE_DIM + l16 * 4];
    int pos = poe[edge];
    __hip_bfloat162 p0 = __float22bfloat162_rn(make_float2(v.x, v.y));
    __hip_bfloat162 p1 = __float22bfloat162_rn(make_float2(v.z, v.w));
    uint2 u = make_uint2(*(uint32_t*)&p0, *(uint32_t*)&p1);
    *(uint2*)&eas[(size_t)pos * EDGE_DIM + l16 * 4] = u;
}

// ---- fused edge-projection + segmented aggregation ----
// z[n] = h[n] + sum_{pos in seg(n)} relu(h[srcs[pos]] + eas[pos] @ W_e + b_e)
__device__ __forceinline__ float blo(uint32_t u) { return __uint_as_float(u << 16); }
__device__ __forceinline__ float bhi(uint32_t u) { return __uint_as_float(u & 0xffff0000u); }

__launch_bounds__(256)
__global__ void agg_fused(const int* __restrict__ offsets, const int* __restrict__ blkstart,
                          const int* __restrict__ srcs, const bf16* __restrict__ eas,
                          const bf16* __restrict__ Wt_e, const float* __restrict__ b_e,
                          const bf16* __restrict__ h, bf16* __restrict__ z) {
    constexpr int P = 136;                         // et pitch (bf16 elems), row = 272 B
    __shared__ __align__(16) bf16 et[AGG_CAP * P]; // 34.8 KB
    __shared__ int srcs_s[AGG_CAP];

    const int b    = blockIdx.x;
    const int tid  = threadIdx.x;
    const int wave = tid >> 6;
    const int lane = tid & 63;
    const int quad = lane >> 4;
    const int l16  = lane & 15;

    const int n0 = blkstart[b], n1 = blkstart[b + 1];
    if (n0 >= n1) return;                          // uniform: safe before barriers
    const int e0 = offsets[n0];
    int e1 = offsets[n1];
    if (e1 > e0 + AGG_CAP) e1 = e0 + AGG_CAP;      // unreachable for maxdeg<64
    const int ne = e1 - e0;

    if (tid < AGG_CAP) srcs_s[tid] = (tid < ne) ? srcs[e0 + tid] : 0;

    // ---- phase 1: e-tile = eas[e0..e1) @ W_e + b_e  (D[ch, edge] layout) ----
    short8 af[2][2];
    float4 bias[2];
    #pragma unroll
    for (int ct = 0; ct < 2; ct++) {
        int chr = (wave * 2 + ct) * 16 + l16;
        #pragma unroll
        for (int ks = 0; ks < 2; ks++)
            af[ct][ks] = *(const short8*)&Wt_e[chr * EDGE_DIM + ks * 32 + quad * 8];
        bias[ct] = *(const float4*)&b_e[(wave * 2 + ct) * 16 + quad * 4];
    }
    const int nsub = (ne + 15) >> 4;
    for (int es = 0; es < nsub; es++) {
        int erow = es * 16 + l16;
        int ge = e0 + erow;
        short8 bf0 = (short8){0,0,0,0,0,0,0,0}, bf1 = bf0;
        if (erow < ne) {
            bf0 = *(const short8*)&eas[(size_t)ge * EDGE_DIM + quad * 8];
            bf1 = *(const short8*)&eas[(size_t)ge * EDGE_DIM + 32 + quad * 8];
        }
        #pragma unroll
        for (int ct = 0; ct < 2; ct++) {
            f32x4 acc = (f32x4){0.f, 0.f, 0.f, 0.f};
            acc = __builtin_amdgcn_mfma_f32_16x16x32_bf16(af[ct][0], bf0, acc, 0, 0, 0);
            acc = __builtin_amdgcn_mfma_f32_16x16x32_bf16(af[ct][1], bf1, acc, 0, 0, 0);
            int row = es * 16 + l16;
            int ch0 = (wave * 2 + ct) * 16 + quad * 4;
            __hip_bfloat162 p0 = __float22bfloat162_rn(make_float2(acc[0] + bias[ct].x, acc[1] + bias[ct].y));
            __hip_bfloat162 p1 = __float22bfloat162_rn(make_float2(acc[2] + bias[ct].z, acc[3] + bias[ct].w));
            *(uint2*)&et[row * P + ch0] = make_uint2(*(uint32_t*)&p0, *(uint32_t*)&p1);
        }
    }
    __syncthreads();

    // ---- phase 2: segmented sum per node, e from LDS, 4 edges in flight ----
    const int c = lane * 2;
    for (int n = n0 + wave; n < n1; n += 4) {
        int s  = offsets[n] - e0;
        int ee = offsets[n + 1] - e0;
        if (ee > ne) ee = ne;
        float2 a = make_float2(0.f, 0.f);
        int i = s;
        for (; i + 3 < ee; i += 4) {
            int s0 = srcs_s[i], s1 = srcs_s[i + 1], s2 = srcs_s[i + 2], s3 = srcs_s[i + 3];
            uint32_t ev0 = *(const uint32_t*)&et[(i + 0) * P + c];
            uint32_t ev1 = *(const uint32_t*)&et[(i + 1) * P + c];
            uint32_t ev2 = *(const uint32_t*)&et[(i + 2) * P + c];
            uint32_t ev3 = *(const uint32_t*)&et[(i + 3) * P + c];
            uint32_t h0 = *(const uint32_t*)&h[(size_t)s0 * HID + c];
            uint32_t h1 = *(const uint32_t*)&h[(size_t)s1 * HID + c];
            uint32_t h2 = *(const uint32_t*)&h[(size_t)s2 * HID + c];
            uint32_t h3 = *(const uint32_t*)&h[(size_t)s3 * HID + c];
            a.x += fmaxf(blo(h0) + blo(ev0), 0.f);
            a.y += fmaxf(bhi(h0) + bhi(ev0), 0.f);
            a.x += fmaxf(blo(h1) + blo(ev1), 0.f);
            a.y += fmaxf(bhi(h1) + bhi(ev1), 0.f);
            a.x += fmaxf(blo(h2) + blo(ev2), 0.f);
            a.y += fmaxf(bhi(h2) + bhi(ev2), 0.f);
            a.x += fmaxf(blo(h3) + blo(ev3), 0.f);
            a.y += fmaxf(bhi(h3) + bhi(ev3), 0.f);
        }
        for (; i < ee; i++) {
            int s0 = srcs_s[i];
            uint32_t ev0 = *(const uint32_t*)&et[i * P + c];
            uint32_t h0 = *(const uint32_t*)&h[(size_t)s0 * HID + c];
            a.x += fmaxf(blo(h0) + blo(ev0), 0.f);
            a.y += fmaxf(bhi(h0) + bhi(ev0), 0.f);
        }
        uint32_t hn = *(const uint32_t*)&h[(size_t)n * HID + c];
        a.x += blo(hn);
        a.y += bhi(hn);
        __hip_bfloat162 p = __float22bfloat162_rn(make_float2(a.x, a.y));
        *(uint32_t*)&z[(size_t)n * HID + c] = *(uint32_t*)&p;
    }
}

extern "C" void kernel_launch(void* const* d_in, const int* in_sizes, int n_in,
                              void* d_out, int out_size, void* d_ws, size_t ws_size,
                              hipStream_t stream) {
    const float* x     = (const float*)d_in[0];
    const int*   ei    = (const int*)d_in[1];
    const float* ea    = (const float*)d_in[2];
    const float* W_in  = (const float*)d_in[3];
    const float* b_in  = (const float*)d_in[4];
    const float* W_e   = (const float*)d_in[5];
    const float* b_e   = (const float*)d_in[6];
    const float* W1    = (const float*)d_in[7];
    const float* b1    = (const float*)d_in[8];
    const float* W2    = (const float*)d_in[9];
    const float* b2    = (const float*)d_in[10];
    const float* W_out = (const float*)d_in[11];
    const float* b_out = (const float*)d_in[12];
    float* out = (float*)d_out;

    char* ws = (char*)d_ws;
    size_t off = 0;
    bf16*  h        = (bf16*) (ws + off); off += (size_t)N_NODES * HID * 2;      // 12.8 MB
    bf16*  z        = (bf16*) (ws + off); off += (size_t)N_NODES * HID * 2;      // 12.8 MB
    bf16*  eas      = (bf16*) (ws + off); off += (size_t)N_EDGES * EDGE_DIM * 2; // 102.4 MB
    int*   counts   = (int*)  (ws + off); off += (size_t)N_NODES * 4;
    int*   offsets  = (int*)  (ws + off); off += (size_t)(N_NODES + 1) * 4;
    int*   cursor   = (int*)  (ws + off); off += (size_t)N_NODES * 4;
    int*   poe      = (int*)  (ws + off); off += (size_t)N_EDGES * 4;
    int*   srcs     = (int*)  (ws + off); off += (size_t)N_EDGES * 4;
    int*   blkstart = (int*)  (ws + off); off += (size_t)(AGG_B + 2) * 4;
    int*   bsum     = (int*)  (ws + off); off += (size_t)SCB * 4;
    int*   bpre     = (int*)  (ws + off); off += (size_t)SCB * 4;
    bf16*  Wt_in    = (bf16*) (ws + off); off += (size_t)HID * IN_CH * 2;
    bf16*  Wt_e     = (bf16*) (ws + off); off += (size_t)HID * EDGE_DIM * 2;
    bf16*  Wt_1     = (bf16*) (ws + off); off += (size_t)HID * HID * 2;
    bf16*  Wt_2     = (bf16*) (ws + off); off += (size_t)HID * HID * 2;
    bf16*  Wt_out   = (bf16*) (ws + off); off += (size_t)OUT_CH * HID * 2;

    // ---- weight prep (one kernel) ----
    wt_prep_all<<<(81920 + 255) / 256, 256, 0, stream>>>(
        W_in, W_e, W1, W2, W_out, Wt_in, Wt_e, Wt_1, Wt_2, Wt_out);

    // ---- counting sort by dst + block ownership table (parallel scan) ----
    hipMemsetAsync(counts, 0, (size_t)N_NODES * 4, stream);
    hist_kernel<<<(N_EDGES + 255) / 256, 256, 0, stream>>>(ei, counts);
    scan_a<<<SCB, 256, 0, stream>>>(counts, bsum);
    scan_b<<<1, 256, 0, stream>>>(bsum, bpre);
    scan_c<<<SCB, 256, 0, stream>>>(counts, bpre, offsets, cursor);
    scan_d<<<SCB, 256, 0, stream>>>(offsets, blkstart);     // 50176 threads >= N_NODES+1
    scatter_perm<<<(N_EDGES + 255) / 256, 256, 0, stream>>>(ei, cursor, poe, srcs);

    // ---- eas = bf16(ea) permuted into sorted order ----
    ea_permute<<<(N_EDGES * 16 + 255) / 256, 256, 0, stream>>>(ea, poe, eas);

    // h = x @ W_in + b_in   (fp32 in, bf16 out)
    gemm_mfma<IN_CH, HID, 64, false, float, bf16>
        <<<(N_NODES + 63) / 64, 256, 0, stream>>>(x, Wt_in, b_in, h, N_NODES);

    for (int layer = 0; layer < 3; ++layer) {
        agg_fused<<<AGG_B + 1, 256, 0, stream>>>(offsets, blkstart, srcs, eas, Wt_e, b_e, h, z);
        gemm_mfma<HID, HID, 64, true, bf16, bf16>
            <<<(N_NODES + 63) / 64, 256, 0, stream>>>(z, Wt_1, b1, h, N_NODES);
        gemm_mfma<HID, HID, 64, true, bf16, bf16>
            <<<(N_NODES + 63) / 64, 256, 0, stream>>>(h, Wt_2, b2, z, N_NODES);
        bf16* t = h; h = z; z = t;   // next layer's h is g2's output
    }

    // out = h @ W_out + b_out (fp32 out)
    gemm_mfma<HID, OUT_CH, 64, false, bf16, float>
        <<<(N_NODES + 63) / 64, 256, 0, stream>>>(h, Wt_out, b_out, out, N_NODES);
}